// Round 2
// baseline (692.834 us; speedup 1.0000x reference)
//
#include <hip/hip_runtime.h>
#include <stdint.h>

typedef unsigned short u16;
typedef short bf16x8 __attribute__((ext_vector_type(8)));
typedef float f32x4 __attribute__((ext_vector_type(4)));

#define NHEADS 8
#define SEQ 1024
#define DM 512
#define DEPTH 64
#define BATCH 8

__device__ __forceinline__ u16 f2bf(float f) {
    union { float f; unsigned u; } v; v.f = f;
    unsigned r = v.u + 0x7FFF + ((v.u >> 16) & 1);
    return (u16)(r >> 16);
}
__device__ __forceinline__ float bf2f(u16 h) {
    union { unsigned u; float f; } v; v.u = ((unsigned)h) << 16;
    return v.f;
}
__device__ __forceinline__ bf16x8 cvt8(const float* p) {
    f32x4 a = *(const f32x4*)p;
    f32x4 b = *(const f32x4*)(p + 4);
    bf16x8 r;
    #pragma unroll
    for (int j = 0; j < 4; j++) { r[j] = (short)f2bf(a[j]); r[j + 4] = (short)f2bf(b[j]); }
    return r;
}

// ---------------------------------------------------------------- transpose
// W f32 [512][512] -> WT bf16 [512][512]; 4 matrices via blockIdx.z
__global__ void __launch_bounds__(256) transpose512(
    const float* __restrict__ w0, const float* __restrict__ w1,
    const float* __restrict__ w2, const float* __restrict__ w3,
    u16* __restrict__ wt)
{
    __shared__ float tile[32][33];
    const float* w = (blockIdx.z == 0) ? w0 : (blockIdx.z == 1) ? w1
                   : (blockIdx.z == 2) ? w2 : w3;
    u16* o = wt + (size_t)blockIdx.z * (DM * DM);
    int rb = blockIdx.y * 32, cb = blockIdx.x * 32;
    int tx = threadIdx.x, ty = threadIdx.y;  // 32 x 8
    #pragma unroll
    for (int k = 0; k < 32; k += 8)
        tile[ty + k][tx] = w[(size_t)(rb + ty + k) * DM + cb + tx];
    __syncthreads();
    #pragma unroll
    for (int k = 0; k < 32; k += 8)
        o[(size_t)(cb + ty + k) * DM + rb + tx] = f2bf(tile[tx][ty + k]);
}

// ---------------------------------------------------------------- GEMM core
// C[8192][512] = in[8192][512] @ W[512][512] + bias,  W given as WT[n][k] bf16.
// Tile 128(M) x 64(N), 4 waves in 2x2, each wave 64x32 (4x2 frags of 16x16).
// LAYOUT 0: A=f32, out bf16 [B,H,S,D]; LAYOUT 1: A=f32, out bf16 [B,H,D,S];
// LAYOUT 2: A=bf16, out f32 [M][N]
template <int LAYOUT>
__device__ __forceinline__ void gemm_tile(
    const void* __restrict__ in_, const u16* __restrict__ wt,
    const float* __restrict__ bias, void* __restrict__ out_)
{
    const int tid = threadIdx.x;
    const int wid = tid >> 6, lane = tid & 63;
    const int wm = wid >> 1, wn = wid & 1;
    const int mb = blockIdx.y * 128 + wm * 64;
    const int nb = blockIdx.x * 64 + wn * 32;
    const int lr = lane & 15;
    const int lk = (lane >> 4) * 8;

    f32x4 acc[4][2];
    #pragma unroll
    for (int i = 0; i < 4; i++)
        #pragma unroll
        for (int j = 0; j < 2; j++) acc[i][j] = (f32x4)0.f;

    for (int ks = 0; ks < DM; ks += 32) {
        bf16x8 a[4], b[2];
        #pragma unroll
        for (int mt = 0; mt < 4; mt++) {
            size_t off = (size_t)(mb + mt * 16 + lr) * DM + ks + lk;
            if (LAYOUT == 2) a[mt] = *(const bf16x8*)((const u16*)in_ + off);
            else             a[mt] = cvt8((const float*)in_ + off);
        }
        #pragma unroll
        for (int nt = 0; nt < 2; nt++)
            b[nt] = *(const bf16x8*)(wt + (size_t)(nb + nt * 16 + lr) * DM + ks + lk);
        #pragma unroll
        for (int mt = 0; mt < 4; mt++)
            #pragma unroll
            for (int nt = 0; nt < 2; nt++)
                acc[mt][nt] = __builtin_amdgcn_mfma_f32_16x16x32_bf16(
                    a[mt], b[nt], acc[mt][nt], 0, 0, 0);
    }

    const int orow0 = (lane >> 4) * 4;
    #pragma unroll
    for (int mt = 0; mt < 4; mt++) {
        #pragma unroll
        for (int nt = 0; nt < 2; nt++) {
            int n = nb + nt * 16 + lr;
            float bv = bias[n];
            #pragma unroll
            for (int r = 0; r < 4; r++) {
                int m = mb + mt * 16 + orow0 + r;
                float val = acc[mt][nt][r] + bv;
                if (LAYOUT == 2) {
                    ((float*)out_)[(size_t)m * DM + n] = val;
                } else {
                    int b_ = m >> 10, s = m & 1023, h = n >> 6, d = n & 63;
                    u16 hv = f2bf(val);
                    if (LAYOUT == 0)
                        ((u16*)out_)[(((size_t)(b_ * NHEADS + h) * SEQ + s) << 6) + d] = hv;
                    else
                        ((u16*)out_)[((size_t)(b_ * NHEADS + h) * DEPTH + d) * SEQ + s] = hv;
                }
            }
        }
    }
}

__global__ void __launch_bounds__(256) qkv_proj(
    const float* __restrict__ q_in, const float* __restrict__ k_in,
    const float* __restrict__ v_in, const u16* __restrict__ wt_base,
    const float* __restrict__ bq, const float* __restrict__ bk,
    const float* __restrict__ bv,
    u16* __restrict__ Qb, u16* __restrict__ Kb, u16* __restrict__ VTb)
{
    int z = blockIdx.z;
    if (z == 0)      gemm_tile<0>(q_in, wt_base,               bq, Qb);
    else if (z == 1) gemm_tile<0>(k_in, wt_base + DM * DM,     bk, Kb);
    else             gemm_tile<1>(v_in, wt_base + 2 * DM * DM, bv, VTb);
}

__global__ void __launch_bounds__(256) out_proj(
    const u16* __restrict__ X, const u16* __restrict__ wto,
    const float* __restrict__ bo, float* __restrict__ out)
{
    gemm_tile<2>(X, wto, bo, out);
}

// ---------------------------------------------------------------- attention
// One block per (h, q-tile of 16, b). 256 threads = 4 waves.
// LDS score stripe Sc[16][1024] fp32 (64 KB), XOR-swizzled on 8-float chunks.
__device__ __forceinline__ int SIDX(int r, int c) {
    int cc = (c >> 3) ^ (r & 3) ^ ((r >> 2) & 3);
    return (r << 10) + (cc << 3) + (c & 7);
}

__global__ void __launch_bounds__(256) attn_kernel(
    const u16* __restrict__ Q, const u16* __restrict__ K,
    const u16* __restrict__ VT, const float* __restrict__ mask,
    const float* __restrict__ addw, float* __restrict__ attn_out,
    u16* __restrict__ X)
{
    __shared__ float Sc[16 * 1024];
    const int h = blockIdx.x, qt = blockIdx.y, b = blockIdx.z;
    const int tid = threadIdx.x, wid = tid >> 6, lane = tid & 63;
    const int lr = lane & 15, lk = (lane >> 4) * 8;
    const int orow0 = (lane >> 4) * 4;
    const size_t head = (size_t)(b * NHEADS + h) * (SEQ * DEPTH);
    const u16* Qh = Q + head + (size_t)qt * 16 * DEPTH;
    const u16* Kh = K + head;
    const u16* Vh = VT + head;  // [64][1024] bf16

    // ---- phase 1: Sc = Q Kt / 8 + mask * -1e9
    bf16x8 af0 = *(const bf16x8*)(Qh + lr * DEPTH + lk);
    bf16x8 af1 = *(const bf16x8*)(Qh + lr * DEPTH + 32 + lk);
    for (int nt = 0; nt < 16; nt++) {
        int scol = (wid << 8) + (nt << 4) + lr;
        f32x4 acc = (f32x4)0.f;
        const u16* kp = Kh + (size_t)scol * DEPTH + lk;
        bf16x8 b0 = *(const bf16x8*)(kp);
        bf16x8 b1 = *(const bf16x8*)(kp + 32);
        acc = __builtin_amdgcn_mfma_f32_16x16x32_bf16(af0, b0, acc, 0, 0, 0);
        acc = __builtin_amdgcn_mfma_f32_16x16x32_bf16(af1, b1, acc, 0, 0, 0);
        float mpen = mask[(b << 10) + scol] * -1e9f;
        #pragma unroll
        for (int r = 0; r < 4; r++)
            Sc[SIDX(orow0 + r, scol)] = acc[r] * 0.125f + mpen;
    }
    __syncthreads();

    // ---- phase 2: softmax + additional_weights; 16 threads per row, 64 cols each
    {
        int row = tid >> 4;
        int ci = (tid & 15) << 6;
        int qg = qt * 16 + row;
        float mx = -3.0e38f;
        #pragma unroll
        for (int j = 0; j < 8; j++) {
            const float* sp = Sc + SIDX(row, ci + j * 8);
            #pragma unroll
            for (int t = 0; t < 8; t++) mx = fmaxf(mx, sp[t]);
        }
        #pragma unroll
        for (int off = 1; off < 16; off <<= 1)
            mx = fmaxf(mx, __shfl_xor(mx, off, 64));
        float sum = 0.f;
        #pragma unroll
        for (int j = 0; j < 8; j++) {
            float* sp = Sc + SIDX(row, ci + j * 8);
            #pragma unroll
            for (int t = 0; t < 8; t++) {
                float p = __expf(sp[t] - mx);
                sp[t] = p;
                sum += p;
            }
        }
        #pragma unroll
        for (int off = 1; off < 16; off <<= 1)
            sum += __shfl_xor(sum, off, 64);
        float inv = 1.0f / sum;
        const float* arow = addw + ((size_t)b * SEQ + qg) * SEQ + ci;
        float* orow = attn_out + (((size_t)(b * NHEADS + h) * SEQ + qg) << 10) + ci;
        #pragma unroll
        for (int j = 0; j < 8; j++) {
            f32x4 aw0 = *(const f32x4*)(arow + j * 8);
            f32x4 aw1 = *(const f32x4*)(arow + j * 8 + 4);
            float* sp = Sc + SIDX(row, ci + j * 8);
            f32x4 o0, o1;
            #pragma unroll
            for (int t = 0; t < 4; t++) {
                float a0 = sp[t] * inv * aw0[t];
                float a1 = sp[t + 4] * inv * aw1[t];
                sp[t] = a0; sp[t + 4] = a1;
                o0[t] = a0; o1[t] = a1;
            }
            *(f32x4*)(orow + j * 8) = o0;
            *(f32x4*)(orow + j * 8 + 4) = o1;
        }
    }
    __syncthreads();

    // ---- phase 3: x = attn @ V via VT; wave wid handles d-range [wid*16, wid*16+16)
    f32x4 xacc = (f32x4)0.f;
    const u16* vrow = Vh + (size_t)((wid << 4) + lr) * SEQ;
    for (int ks = 0; ks < SEQ; ks += 32) {
        const float* ap = Sc + SIDX(lr, ks + lk);
        bf16x8 a;
        #pragma unroll
        for (int j = 0; j < 8; j++) a[j] = (short)f2bf(ap[j]);
        bf16x8 bv = *(const bf16x8*)(vrow + ks + lk);
        xacc = __builtin_amdgcn_mfma_f32_16x16x32_bf16(a, bv, xacc, 0, 0, 0);
    }
    int d = (h << 6) + (wid << 4) + lr;
    #pragma unroll
    for (int r = 0; r < 4; r++)
        X[((size_t)(b << 10) + qt * 16 + orow0 + r) * DM + d] = f2bf(xacc[r]);
}

// ---------------------------------------------------------------- launch
extern "C" void kernel_launch(void* const* d_in, const int* in_sizes, int n_in,
                              void* d_out, int out_size, void* d_ws, size_t ws_size,
                              hipStream_t stream)
{
    const float* q_in = (const float*)d_in[0];
    const float* k_in = (const float*)d_in[1];
    const float* v_in = (const float*)d_in[2];
    const float* mask = (const float*)d_in[3];
    const float* addw = (const float*)d_in[4];
    const float* wq = (const float*)d_in[5];
    const float* bq = (const float*)d_in[6];
    const float* wk = (const float*)d_in[7];
    const float* bk = (const float*)d_in[8];
    const float* wv = (const float*)d_in[9];
    const float* bv = (const float*)d_in[10];
    const float* wo = (const float*)d_in[11];
    const float* bo = (const float*)d_in[12];

    u16* ws = (u16*)d_ws;
    u16* wt = ws;                        // 4 * 512*512 bf16
    u16* Qb = ws + 4 * DM * DM;          // [B,H,S,D] bf16
    u16* Kb = Qb + BATCH * NHEADS * SEQ * DEPTH;
    u16* VTb = Kb + BATCH * NHEADS * SEQ * DEPTH;
    u16* Xb = VTb + BATCH * NHEADS * SEQ * DEPTH;

    float* out0 = (float*)d_out;                             // [B,S,512] f32
    float* attn_out = out0 + (size_t)BATCH * SEQ * DM;       // [B,H,S,S] f32

    transpose512<<<dim3(16, 16, 4), dim3(32, 8), 0, stream>>>(wq, wk, wv, wo, wt);
    qkv_proj<<<dim3(8, 64, 3), 256, 0, stream>>>(q_in, k_in, v_in, wt, bq, bk, bv,
                                                 Qb, Kb, VTb);
    attn_kernel<<<dim3(8, 64, 8), 256, 0, stream>>>(Qb, Kb, VTb, mask, addw,
                                                    attn_out, Xb);
    out_proj<<<dim3(8, 64, 1), 256, 0, stream>>>(Xb, wt + 3 * DM * DM, bo, out0);
}

// Round 4
// 581.659 us; speedup vs baseline: 1.1911x; 1.1911x over previous
//
#include <hip/hip_runtime.h>
#include <stdint.h>

typedef unsigned short u16;
typedef short bf16x8 __attribute__((ext_vector_type(8)));
typedef float f32x4 __attribute__((ext_vector_type(4)));
typedef u16 u16x8 __attribute__((ext_vector_type(8)));

#define NHEADS 8
#define SEQ 1024
#define DM 512
#define DEPTH 64
#define BATCH 8
#define PSTRIDE 1032   // 1024 + 8 bf16 pad -> +16B per row -> bank shift of 4

__device__ __forceinline__ u16 f2bf(float f) {
    union { float f; unsigned u; } v; v.f = f;
    unsigned r = v.u + 0x7FFF + ((v.u >> 16) & 1);
    return (u16)(r >> 16);
}

// ---------------------------------------------------------------- prep
// W f32 [512][512] -> WT bf16 [512][512]; 4 matrices via blockIdx.z
__global__ void __launch_bounds__(256) transpose512(
    const float* __restrict__ w0, const float* __restrict__ w1,
    const float* __restrict__ w2, const float* __restrict__ w3,
    u16* __restrict__ wt)
{
    __shared__ float tile[32][33];
    const float* w = (blockIdx.z == 0) ? w0 : (blockIdx.z == 1) ? w1
                   : (blockIdx.z == 2) ? w2 : w3;
    u16* o = wt + (size_t)blockIdx.z * (DM * DM);
    int rb = blockIdx.y * 32, cb = blockIdx.x * 32;
    int tx = threadIdx.x, ty = threadIdx.y;  // 32 x 8
    #pragma unroll
    for (int k = 0; k < 32; k += 8)
        tile[ty + k][tx] = w[(size_t)(rb + ty + k) * DM + cb + tx];
    __syncthreads();
    #pragma unroll
    for (int k = 0; k < 32; k += 8)
        o[(size_t)(cb + ty + k) * DM + rb + tx] = f2bf(tile[tx][ty + k]);
}

// f32 -> bf16 for the three activation inputs
__global__ void __launch_bounds__(256) conv_bf16(
    const float* __restrict__ q, const float* __restrict__ k,
    const float* __restrict__ v,
    u16* __restrict__ oq, u16* __restrict__ ok, u16* __restrict__ ov)
{
    const float* src = (blockIdx.z == 0) ? q : (blockIdx.z == 1) ? k : v;
    u16* dst = (blockIdx.z == 0) ? oq : (blockIdx.z == 1) ? ok : ov;
    size_t i = ((size_t)blockIdx.x * 256 + threadIdx.x) * 8;
    f32x4 a = *(const f32x4*)(src + i);
    f32x4 b = *(const f32x4*)(src + i + 4);
    u16x8 o;
    #pragma unroll
    for (int j = 0; j < 4; j++) { o[j] = f2bf(a[j]); o[j + 4] = f2bf(b[j]); }
    *(u16x8*)(dst + i) = o;
}

// ---------------------------------------------------------------- GEMM core
// C[8192][512] = A[8192][512] @ W[512][512] + bias, W as WT[n][k], all bf16 in.
// Block tile 128x128, 4 waves 2x2, wave = 64x64 (4x4 frags), 16 MFMA / 8 loads.
// LAYOUT 0: out bf16 [B,H,S,D]; LAYOUT 1: out bf16 [B,H,D,S] via swapped
// operands (computes C^T tile so stores are s-contiguous); LAYOUT 2: f32 [M][N]
template <int LAYOUT>
__device__ __forceinline__ void gemm_tile(
    const u16* __restrict__ A, const u16* __restrict__ wt,
    const float* __restrict__ bias, void* __restrict__ out_)
{
    const int tid = threadIdx.x;
    const int wid = tid >> 6, lane = tid & 63;
    const int wm = wid >> 1, wn = wid & 1;
    const int mb = blockIdx.y * 128 + wm * 64;
    const int nb = blockIdx.x * 128 + wn * 64;
    const int lr = lane & 15, g = lane >> 4, lk = g * 8;

    f32x4 acc[4][4];
    #pragma unroll
    for (int i = 0; i < 4; i++)
        #pragma unroll
        for (int j = 0; j < 4; j++) acc[i][j] = (f32x4)0.f;

    for (int ks = 0; ks < DM; ks += 32) {
        bf16x8 a[4], bf[4];
        #pragma unroll
        for (int mt = 0; mt < 4; mt++)
            a[mt] = *(const bf16x8*)(A + (size_t)(mb + mt * 16 + lr) * DM + ks + lk);
        #pragma unroll
        for (int nt = 0; nt < 4; nt++)
            bf[nt] = *(const bf16x8*)(wt + (size_t)(nb + nt * 16 + lr) * DM + ks + lk);
        #pragma unroll
        for (int mt = 0; mt < 4; mt++)
            #pragma unroll
            for (int nt = 0; nt < 4; nt++) {
                if (LAYOUT == 1)
                    acc[mt][nt] = __builtin_amdgcn_mfma_f32_16x16x32_bf16(
                        bf[nt], a[mt], acc[mt][nt], 0, 0, 0);
                else
                    acc[mt][nt] = __builtin_amdgcn_mfma_f32_16x16x32_bf16(
                        a[mt], bf[nt], acc[mt][nt], 0, 0, 0);
            }
    }

    #pragma unroll
    for (int mt = 0; mt < 4; mt++) {
        #pragma unroll
        for (int nt = 0; nt < 4; nt++) {
            #pragma unroll
            for (int r = 0; r < 4; r++) {
                if (LAYOUT == 1) {
                    // C^T tile: col = m(s)-index = lr, row = n(d)-index
                    int m = mb + mt * 16 + lr;
                    int n = nb + nt * 16 + 4 * g + r;
                    float val = acc[mt][nt][r] + bias[n];
                    int b_ = m >> 10, s = m & 1023, h = n >> 6, d = n & 63;
                    ((u16*)out_)[((size_t)((b_ * NHEADS + h) << 6) + d) * SEQ + s] = f2bf(val);
                } else {
                    int n = nb + nt * 16 + lr;
                    int m = mb + mt * 16 + 4 * g + r;
                    float val = acc[mt][nt][r] + bias[n];
                    if (LAYOUT == 2) {
                        ((float*)out_)[(size_t)m * DM + n] = val;
                    } else {
                        int b_ = m >> 10, s = m & 1023, h = n >> 6, d = n & 63;
                        ((u16*)out_)[(((size_t)(b_ * NHEADS + h) * SEQ + s) << 6) + d] = f2bf(val);
                    }
                }
            }
        }
    }
}

__global__ void __launch_bounds__(256) qkv_proj(
    const u16* __restrict__ qbf, const u16* __restrict__ kbf,
    const u16* __restrict__ vbf, const u16* __restrict__ wt_base,
    const float* __restrict__ bq, const float* __restrict__ bk,
    const float* __restrict__ bv,
    u16* __restrict__ Qb, u16* __restrict__ Kb, u16* __restrict__ VTb)
{
    int z = blockIdx.z;
    if (z == 0)      gemm_tile<0>(qbf, wt_base,               bq, Qb);
    else if (z == 1) gemm_tile<0>(kbf, wt_base + DM * DM,     bk, Kb);
    else             gemm_tile<1>(vbf, wt_base + 2 * DM * DM, bv, VTb);
}

__global__ void __launch_bounds__(256) out_proj(
    const u16* __restrict__ X, const u16* __restrict__ wto,
    const float* __restrict__ bo, float* __restrict__ out)
{
    gemm_tile<2>(X, wto, bo, out);
}

// ---------------------------------------------------------------- attention
// One block per (h, 16-row q-tile, b); 256 threads = 4 waves, wave owns 256
// K-columns. Scores live in registers (C-layout); softmax via quad shuffles +
// 4x16 LDS cross-wave; P round-trips LDS as bf16 only for the PV A-operand
// layout transform.
__global__ void __launch_bounds__(256) attn_kernel(
    const u16* __restrict__ Q, const u16* __restrict__ K,
    const u16* __restrict__ VT, const float* __restrict__ mask,
    const float* __restrict__ addw, float* __restrict__ attn_out,
    u16* __restrict__ X)
{
    __shared__ u16 Pl[16 * PSTRIDE];
    __shared__ float redm[4][16];
    __shared__ float reds[4][16];
    const int h = blockIdx.x, qt = blockIdx.y, b = blockIdx.z;
    const int tid = threadIdx.x, wid = tid >> 6, lane = tid & 63;
    const int lr = lane & 15, g = lane >> 4, lk = g * 8;
    const size_t head = (size_t)(b * NHEADS + h) * (SEQ * DEPTH);
    const u16* Qh = Q + head + (size_t)qt * 16 * DEPTH;
    const u16* Kh = K + head;
    const u16* Vh = VT + head;  // [64][1024] bf16
    const int cbase = (wid << 8) + lr;

    // ---- phase 1: S = Q K^T in registers (wave covers cols cbase + nt*16)
    bf16x8 af0 = *(const bf16x8*)(Qh + lr * DEPTH + lk);
    bf16x8 af1 = *(const bf16x8*)(Qh + lr * DEPTH + 32 + lk);
    f32x4 acc[16];
    #pragma unroll
    for (int nt = 0; nt < 16; nt++) acc[nt] = (f32x4)0.f;
    #pragma unroll
    for (int nt = 0; nt < 16; nt++) {
        const u16* kp = Kh + (size_t)(cbase + (nt << 4)) * DEPTH + lk;
        bf16x8 b0 = *(const bf16x8*)kp;
        bf16x8 b1 = *(const bf16x8*)(kp + 32);
        acc[nt] = __builtin_amdgcn_mfma_f32_16x16x32_bf16(af0, b0, acc[nt], 0, 0, 0);
        acc[nt] = __builtin_amdgcn_mfma_f32_16x16x32_bf16(af1, b1, acc[nt], 0, 0, 0);
    }

    // ---- scale + mask + in-register row max (rows 4g..4g+3 of this q-tile)
    const float* mrow = mask + ((size_t)b << 10);
    float mx[4];
    #pragma unroll
    for (int r = 0; r < 4; r++) mx[r] = -3.0e38f;
    #pragma unroll
    for (int nt = 0; nt < 16; nt++) {
        float mp = mrow[cbase + (nt << 4)] * -1e9f;
        #pragma unroll
        for (int r = 0; r < 4; r++) {
            acc[nt][r] = acc[nt][r] * 0.125f + mp;
            mx[r] = fmaxf(mx[r], acc[nt][r]);
        }
    }
    #pragma unroll
    for (int off = 1; off < 16; off <<= 1)
        #pragma unroll
        for (int r = 0; r < 4; r++)
            mx[r] = fmaxf(mx[r], __shfl_xor(mx[r], off, 64));
    if (lr < 4)
        redm[wid][4 * g + lr] = (lr == 0) ? mx[0] : (lr == 1) ? mx[1]
                              : (lr == 2) ? mx[2] : mx[3];
    __syncthreads();
    float gm[4];
    #pragma unroll
    for (int r = 0; r < 4; r++)
        gm[r] = fmaxf(fmaxf(redm[0][4 * g + r], redm[1][4 * g + r]),
                      fmaxf(redm[2][4 * g + r], redm[3][4 * g + r]));

    // ---- exp + row sum
    float sm[4];
    #pragma unroll
    for (int r = 0; r < 4; r++) sm[r] = 0.f;
    #pragma unroll
    for (int nt = 0; nt < 16; nt++)
        #pragma unroll
        for (int r = 0; r < 4; r++) {
            float p = __expf(acc[nt][r] - gm[r]);
            acc[nt][r] = p;
            sm[r] += p;
        }
    #pragma unroll
    for (int off = 1; off < 16; off <<= 1)
        #pragma unroll
        for (int r = 0; r < 4; r++)
            sm[r] += __shfl_xor(sm[r], off, 64);
    if (lr < 4)
        reds[wid][4 * g + lr] = (lr == 0) ? sm[0] : (lr == 1) ? sm[1]
                              : (lr == 2) ? sm[2] : sm[3];
    __syncthreads();
    float iv[4];
    #pragma unroll
    for (int r = 0; r < 4; r++)
        iv[r] = 1.0f / (reds[0][4 * g + r] + reds[1][4 * g + r] +
                        reds[2][4 * g + r] + reds[3][4 * g + r]);

    // ---- phase 2: scale by 1/sum * addw, write attn f32, stash P bf16 in LDS
    const int qr0 = qt * 16 + 4 * g;
    size_t awr = ((size_t)((b << 10) + qr0) << 10);
    size_t aor = ((size_t)(((b * NHEADS + h) << 10) + qr0) << 10);
    #pragma unroll
    for (int nt = 0; nt < 16; nt++) {
        int col = cbase + (nt << 4);
        #pragma unroll
        for (int r = 0; r < 4; r++) {
            float val = acc[nt][r] * iv[r] * addw[awr + ((size_t)r << 10) + col];
            attn_out[aor + ((size_t)r << 10) + col] = val;
            Pl[(4 * g + r) * PSTRIDE + col] = f2bf(val);
        }
    }
    __syncthreads();

    // ---- phase 3: X = P @ V; wave wid handles d in [wid*16, wid*16+16)
    f32x4 x = (f32x4)0.f;
    const u16* vrow = Vh + (size_t)((wid << 4) + lr) * SEQ;
    for (int ks = 0; ks < SEQ; ks += 32) {
        bf16x8 a = *(const bf16x8*)(Pl + lr * PSTRIDE + ks + lk);
        bf16x8 bv = *(const bf16x8*)(vrow + ks + lk);
        x = __builtin_amdgcn_mfma_f32_16x16x32_bf16(a, bv, x, 0, 0, 0);
    }
    int d = (h << 6) + (wid << 4) + lr;
    #pragma unroll
    for (int r = 0; r < 4; r++)
        X[((size_t)((b << 10) + qt * 16 + 4 * g + r)) * DM + d] = f2bf(x[r]);
}

// ---------------------------------------------------------------- launch
extern "C" void kernel_launch(void* const* d_in, const int* in_sizes, int n_in,
                              void* d_out, int out_size, void* d_ws, size_t ws_size,
                              hipStream_t stream)
{
    const float* q_in = (const float*)d_in[0];
    const float* k_in = (const float*)d_in[1];
    const float* v_in = (const float*)d_in[2];
    const float* mask = (const float*)d_in[3];
    const float* addw = (const float*)d_in[4];
    const float* wq = (const float*)d_in[5];
    const float* bq = (const float*)d_in[6];
    const float* wk = (const float*)d_in[7];
    const float* bk = (const float*)d_in[8];
    const float* wv = (const float*)d_in[9];
    const float* bv = (const float*)d_in[10];
    const float* wo = (const float*)d_in[11];
    const float* bo = (const float*)d_in[12];

    const size_t ACT = (size_t)BATCH * SEQ * DM;   // 4,194,304 elements

    // workspace: 34 MB total (same footprint that passed in R2)
    u16* ws = (u16*)d_ws;
    u16* wt  = ws;                    // 4 * 512*512 bf16      (2 MB)
    u16* Qb  = wt + 4 * DM * DM;      // [B,H,S,D] bf16        (8 MB)
    u16* Kb  = Qb + ACT;              // [B,H,S,D] bf16        (8 MB)
    u16* VTb = Kb + ACT;              // [B,H,D,S] bf16        (8 MB)
    u16* Xb  = VTb + ACT;             // [B,S,DM]  bf16        (8 MB)

    float* out0 = (float*)d_out;                         // [B,S,512] f32
    float* attn_out = out0 + ACT;                        // [B,H,S,S] f32 (268 MB)

    // bf16-converted activations live in the attn_out region of d_out:
    // written by conv_bf16, consumed by qkv_proj, then fully overwritten by
    // attn_kernel's attn output. 24 MB << 268 MB.
    u16* qbf = (u16*)attn_out;
    u16* kbf = qbf + ACT;
    u16* vbf = kbf + ACT;

    transpose512<<<dim3(16, 16, 4), dim3(32, 8), 0, stream>>>(wq, wk, wv, wo, wt);
    conv_bf16<<<dim3(2048, 1, 3), 256, 0, stream>>>(q_in, k_in, v_in, qbf, kbf, vbf);
    qkv_proj<<<dim3(4, 64, 3), 256, 0, stream>>>(qbf, kbf, vbf, wt, bq, bk, bv,
                                                 Qb, Kb, VTb);
    attn_kernel<<<dim3(8, 64, 8), 256, 0, stream>>>(Qb, Kb, VTb, mask, addw,
                                                    attn_out, Xb);
    out_proj<<<dim3(4, 64, 1), 256, 0, stream>>>(Xb, wt + 3 * DM * DM, bo, out0);
}